// Round 6
// baseline (10336.381 us; speedup 1.0000x reference)
//
#include <hip/hip_runtime.h>

#define NCU     256
#define TPB     512      // 8 waves
#define HID     2048
#define EMBD    512
#define HIN     2560
#define TSTEPS  4096
#define NCH     256

typedef unsigned long long u64;
typedef float f32x4 __attribute__((ext_vector_type(4)));

__device__ __forceinline__ float sig_(float x) { return 1.f / (1.f + __expf(-x)); }
__device__ __forceinline__ float th_(float x)  { float e = __expf(2.f * x); return 1.f - 2.f / (e + 1.f); }

__device__ __forceinline__ u64 ld_slot(const u64* p) {
    return __hip_atomic_load(p, __ATOMIC_RELAXED, __HIP_MEMORY_SCOPE_AGENT);
}

__device__ __forceinline__ float dot4(f32x4 a, f32x4 b) {
    return a.x * b.x + a.y * b.y + a.z * b.z + a.w * b.w;
}

// Loop-body register pin: volatile => cannot be hoisted/duplicated/remat'd.
// Redefines the value in VGPRs every iteration, making it loop-carried.
#define PIN(v) asm volatile("" : "+v"(v))

extern "C" __global__ void __launch_bounds__(TPB, 2)
lstm_persist(const int* __restrict__ seq,
             const float* __restrict__ emb,
             const float* __restrict__ Wf, const float* __restrict__ bf,
             const float* __restrict__ Wi, const float* __restrict__ bi,
             const float* __restrict__ Wo, const float* __restrict__ bo,
             const float* __restrict__ Wc, const float* __restrict__ bc,
             const float* __restrict__ Wout, const float* __restrict__ bout,
             float* __restrict__ dout,
             u64* __restrict__ hbuf)        // [2][2048] tagged ping-pong: hi32=step, lo32=float bits
{
    const int b    = blockIdx.x;          // CU id == output char id
    const int tid  = threadIdx.x;
    const int wave = tid >> 6;
    const int lane = tid & 63;
    const int hidx = b * 8 + wave;        // h index owned by this wave

    __shared__ float hs[HID];
    __shared__ float wpart[8];

    // ---- persistent weights as f32x4 tuples (dwordx4-coalesced loads) ----
    // wh[g][j]: cols EMBD + 4*lane + 256*j + {0..3}   (j = 0..7  -> 2048 recurrent cols)
    // wx[g][j]: cols        4*lane + 256*j + {0..3}   (j = 0..1  ->  512 input cols)
    // wr      : Wout[b][4*tid + {0..3}]
    f32x4 wh[4][8], wx[4][2], wr;
    {
        const float* Wm[4] = { Wf, Wi, Wo, Wc };
        #pragma unroll
        for (int g = 0; g < 4; ++g) {
            const float* base = Wm[g] + (size_t)hidx * HIN;
            #pragma unroll
            for (int j = 0; j < 8; ++j)
                wh[g][j] = *(const f32x4*)(base + EMBD + 4 * lane + 256 * j);
            #pragma unroll
            for (int j = 0; j < 2; ++j)
                wx[g][j] = *(const f32x4*)(base + 4 * lane + 256 * j);
        }
        wr = *(const f32x4*)(Wout + (size_t)b * HID + 4 * tid);
    }
    const float bias0 = bf[hidx], bias1 = bi[hidx], bias2 = bo[hidx], bias3 = bc[hidx];
    const float boutb = bout[b];

    float c = 0.f;
    int ch = seq[0];

    for (int t = 0; t <= TSTEPS; ++t) {
        // ---- re-pin all weights: forces VGPR residency across the whole loop ----
        #pragma unroll
        for (int g = 0; g < 4; ++g) {
            #pragma unroll
            for (int j = 0; j < 8; ++j) PIN(wh[g][j]);
            PIN(wx[g][0]); PIN(wx[g][1]);
        }
        PIN(wr);

        // ---- x-contribution first (independent of h, off the critical path) ----
        float a0 = bias0, a1 = bias1, a2 = bias2, a3 = bias3;
        if (t < TSTEPS) {
            const float* erow = emb + (size_t)ch * EMBD;
            const f32x4 xv0 = *(const f32x4*)(erow + 4 * lane);
            const f32x4 xv1 = *(const f32x4*)(erow + 4 * lane + 256);
            a0 += dot4(wx[0][0], xv0) + dot4(wx[0][1], xv1);
            a1 += dot4(wx[1][0], xv0) + dot4(wx[1][1], xv1);
            a2 += dot4(wx[2][0], xv0) + dot4(wx[2][1], xv1);
            a3 += dot4(wx[3][0], xv0) + dot4(wx[3][1], xv1);
        }
        const int ch_next = (t + 1 < TSTEPS) ? seq[t + 1] : 0;

        // ---- stage h_t into LDS: poll tagged slots (the store IS the arrival signal) ----
        if (t == 0) {
            #pragma unroll
            for (int k = 0; k < 4; ++k) hs[tid + 512 * k] = 0.f;
        } else {
            const u64* src = hbuf + (size_t)(t & 1) * HID;
            const u64* p0 = src + tid;
            const u64* p1 = src + tid + 512;
            const u64* p2 = src + tid + 1024;
            const u64* p3 = src + tid + 1536;
            const unsigned tt = (unsigned)t;
            u64 v0 = ld_slot(p0), v1 = ld_slot(p1), v2 = ld_slot(p2), v3 = ld_slot(p3);
            while (((unsigned)(v0 >> 32) != tt) | ((unsigned)(v1 >> 32) != tt) |
                   ((unsigned)(v2 >> 32) != tt) | ((unsigned)(v3 >> 32) != tt)) {
                __builtin_amdgcn_s_sleep(1);
                v0 = ld_slot(p0); v1 = ld_slot(p1); v2 = ld_slot(p2); v3 = ld_slot(p3);
            }
            hs[tid]        = __uint_as_float((unsigned)v0);
            hs[tid + 512]  = __uint_as_float((unsigned)v1);
            hs[tid + 1024] = __uint_as_float((unsigned)v2);
            hs[tid + 1536] = __uint_as_float((unsigned)v3);
        }
        __syncthreads();                                      // BAR B: hs ready

        // ---- gates (critical path): 8x ds_read_b128 + 128 FMA ----
        if (t < TSTEPS) {
            #pragma unroll
            for (int j = 0; j < 8; ++j) {
                const f32x4 hv = *(const f32x4*)&hs[4 * lane + 256 * j];
                a0 += dot4(wh[0][j], hv);
                a1 += dot4(wh[1][j], hv);
                a2 += dot4(wh[2][j], hv);
                a3 += dot4(wh[3][j], hv);
            }
            #pragma unroll
            for (int m = 32; m >= 1; m >>= 1) {               // butterfly: all lanes get sums
                a0 += __shfl_xor(a0, m, 64);
                a1 += __shfl_xor(a1, m, 64);
                a2 += __shfl_xor(a2, m, 64);
                a3 += __shfl_xor(a3, m, 64);
            }
            const float f = sig_(a0);
            const float i = sig_(a1);
            const float o = sig_(a2);
            const float g = th_(a3);
            c = f * c + i * g;                                // replicated across lanes
            const float hn = o * th_(c);
            if (lane == 0) {
                const u64 pk = ((u64)(unsigned)(t + 1) << 32) | (u64)__float_as_uint(hn);
                __hip_atomic_store(hbuf + (size_t)((t + 1) & 1) * HID + hidx, pk,
                                   __ATOMIC_RELAXED, __HIP_MEMORY_SCOPE_AGENT);
                if (t == TSTEPS - 1) {
                    dout[(size_t)TSTEPS * NCH + hidx]       = hn;   // h_last
                    dout[(size_t)TSTEPS * NCH + HID + hidx] = c;    // c_last
                }
            }
        }

        // ---- out[t-1][b] from staged h_t — after the h release, overlaps others' polls ----
        if (t > 0) {
            const f32x4 hv = *(const f32x4*)&hs[4 * tid];
            float op = dot4(wr, hv);
            #pragma unroll
            for (int m = 32; m >= 1; m >>= 1) op += __shfl_xor(op, m, 64);
            if (lane == 0) wpart[wave] = op;
        }
        __syncthreads();                                      // BAR C: wpart ready, hs reusable

        if (tid == 0 && t > 0) {
            float s = wpart[0] + wpart[1] + wpart[2] + wpart[3]
                    + wpart[4] + wpart[5] + wpart[6] + wpart[7];
            dout[(size_t)(t - 1) * NCH + b] = s + boutb;
        }
        ch = ch_next;
    }
}

extern "C" void kernel_launch(void* const* d_in, const int* in_sizes, int n_in,
                              void* d_out, int out_size, void* d_ws, size_t ws_size,
                              hipStream_t stream) {
    const int*   seq  = (const int*)d_in[0];
    const float* emb  = (const float*)d_in[1];
    const float* Wf   = (const float*)d_in[2];
    const float* bf   = (const float*)d_in[3];
    const float* Wi   = (const float*)d_in[4];
    const float* bi   = (const float*)d_in[5];
    const float* Wo   = (const float*)d_in[6];
    const float* bo   = (const float*)d_in[7];
    const float* Wc   = (const float*)d_in[8];
    const float* bc   = (const float*)d_in[9];
    const float* Wout = (const float*)d_in[10];
    const float* bout = (const float*)d_in[11];
    float* dout = (float*)d_out;
    u64*   hbuf = (u64*)d_ws;                               // [2][2048] tagged slots

    hipMemsetAsync(d_ws, 0, 2 * HID * sizeof(u64), stream); // tags <- 0 (!= any wanted step >=1)
    hipLaunchKernelGGL(lstm_persist, dim3(NCU), dim3(TPB), 0, stream,
                       seq, emb, Wf, bf, Wi, bi, Wo, bo, Wc, bc, Wout, bout,
                       dout, hbuf);
}